// Round 7
// baseline (53.981 us; speedup 1.0000x reference)
//
#include <hip/hip_runtime.h>
#include <hip/hip_bf16.h>

#define B_N 2048
#define E_N 64
#define D_N 512
#define O_N 512
#define NSL 8     // k-slices (split-K)
#define KS  64    // k per slice
#define XLD 72    // xs row stride (ushorts)

typedef __bf16 bf16x8 __attribute__((ext_vector_type(8)));
typedef float  f32x4  __attribute__((ext_vector_type(4)));

__device__ __forceinline__ unsigned cvt2(float a, float b) {
  union { __hip_bfloat162 h; unsigned u; } c;
  c.h = __float22bfloat162_rn(make_float2(a, b));
  return c.u;   // low 16 = a, high 16 = b
}

// 8 blocks x 256: global-atomic bucketing (out rows are order-invariant).
__global__ __launch_bounds__(256)
void bucket_kernel(const int* __restrict__ opt, int* __restrict__ cnt,
                   int* __restrict__ list) {
  int b = blockIdx.x * 256 + threadIdx.x;
  int e = opt[b];
  int slot = atomicAdd(&cnt[e], 1);
  list[e * B_N + slot] = b;
}

// out[b][:] = bias[opt[b]][:]  (atomic partials accumulate on top)
__global__ __launch_bounds__(256)
void bias_init_kernel(const int* __restrict__ opt, const float* __restrict__ bias,
                      float* __restrict__ out) {
  int gid = blockIdx.x * 256 + threadIdx.x;   // 1024 blocks -> 262144 float4
  int b  = gid >> 7;
  int o4 = gid & 127;
  int e  = opt[b];
  reinterpret_cast<float4*>(out)[(size_t)b * 128 + o4] =
      reinterpret_cast<const float4*>(bias)[(size_t)e * 128 + o4];
}

// Split-K grouped GEMM: block = (expert e, k-slice s of 64). The W slice is a
// CONTIGUOUS 128 KB region -> reg-staged (16 indep float4/thread) -> bf16 LDS.
// 8 waves each own 64 out-cols; B-fragments live in registers (loaded once);
// partials accumulate into out via coalesced fp32 atomicAdd.
__global__ __launch_bounds__(512, 4)
void gemm_kernel(const float* __restrict__ x, const float* __restrict__ w,
                 const int* __restrict__ cnt, const int* __restrict__ list,
                 float* __restrict__ out) {
  __shared__ unsigned short ws[KS * 512];   // 64 KB bf16 [k][c], c XOR-swizzled
  __shared__ unsigned short xs[64 * XLD];   // 9 KB bf16 gathered x rows
  __shared__ int sl[64];

  const int e    = blockIdx.x;
  const int s    = blockIdx.y;
  const int t    = threadIdx.x;
  const int lane = t & 63;
  const int wave = t >> 6;
  const int n    = cnt[e];
  if (n == 0) return;

  const int m_in = lane & 15;
  const int g    = lane >> 4;
  const int* mylist = list + e * B_N;

  // ---- stage W slice: contiguous 128 KB fp32 -> bf16 LDS (swizzled) ----
  const float* wsl = w + (size_t)e * D_N * O_N + (size_t)s * KS * O_N;
#pragma unroll
  for (int i = 0; i < 16; ++i) {
    int idx = t + i * 512;                 // float4 id, fully sequential
    int k   = idx >> 7;                    // 128 float4 per k-row
    int c0  = (idx & 127) * 4;
    const float4 f = *reinterpret_cast<const float4*>(wsl + (size_t)idx * 4);
    *reinterpret_cast<uint2*>(&ws[k * 512 + (c0 ^ ((k & 15) << 2))]) =
        make_uint2(cvt2(f.x, f.y), cvt2(f.z, f.w));
  }
  __syncthreads();

  // ---- load this wave's 8 B-fragments into registers (once) ----
  union { unsigned short us[8]; bf16x8 v; } frag[4][2];
#pragma unroll
  for (int cg = 0; cg < 4; ++cg) {
    const int c = wave * 64 + cg * 16 + m_in;
#pragma unroll
    for (int ks = 0; ks < 2; ++ks) {
#pragma unroll
      for (int j = 0; j < 8; ++j) {
        const int kk = ks * 32 + g * 8 + j;
        frag[cg][ks].us[j] = ws[kk * 512 + (c ^ ((kk & 15) << 2))];
      }
    }
  }

  for (int m0 = 0; m0 < n; m0 += 64) {
    // ---- stage up to 64 gathered x rows (this k-slice only) ----
#pragma unroll
    for (int i = 0; i < 2; ++i) {
      int idx = t + i * 512;               // 1024 float4 = 64 rows x 16
      int row = idx >> 4;
      int c4  = idx & 15;
      int sm  = m0 + row;
      uint2 v = make_uint2(0u, 0u);
      int b = 0;
      if (sm < n) {
        b = mylist[sm];
        const float4 xv = *reinterpret_cast<const float4*>(
            x + (size_t)b * D_N + s * KS + c4 * 4);
        v = make_uint2(cvt2(xv.x, xv.y), cvt2(xv.z, xv.w));
      }
      if (c4 == 0) sl[row] = b;
      *reinterpret_cast<uint2*>(&xs[row * XLD + c4 * 4]) = v;
    }
    __syncthreads();

#pragma unroll
    for (int mc = 0; mc < 2; ++mc) {
      f32x4 acc[2][4];
#pragma unroll
      for (int rg = 0; rg < 2; ++rg)
#pragma unroll
        for (int cg = 0; cg < 4; ++cg) acc[rg][cg] = (f32x4){0.f, 0.f, 0.f, 0.f};

#pragma unroll
      for (int ks = 0; ks < 2; ++ks) {
        union { uint4 u; bf16x8 v; } a0, a1;
        a0.u = *reinterpret_cast<const uint4*>(
            &xs[(mc * 32 + m_in) * XLD + ks * 32 + g * 8]);
        a1.u = *reinterpret_cast<const uint4*>(
            &xs[(mc * 32 + 16 + m_in) * XLD + ks * 32 + g * 8]);
#pragma unroll
        for (int cg = 0; cg < 4; ++cg) {
          acc[0][cg] = __builtin_amdgcn_mfma_f32_16x16x32_bf16(
              a0.v, frag[cg][ks].v, acc[0][cg], 0, 0, 0);
          acc[1][cg] = __builtin_amdgcn_mfma_f32_16x16x32_bf16(
              a1.v, frag[cg][ks].v, acc[1][cg], 0, 0, 0);
        }
      }

      // D layout (m89-verified): col = lane&15, row = g*4 + r
#pragma unroll
      for (int rg = 0; rg < 2; ++rg)
#pragma unroll
        for (int cg = 0; cg < 4; ++cg)
#pragma unroll
          for (int r = 0; r < 4; ++r) {
            int rl = mc * 32 + rg * 16 + g * 4 + r;
            if (m0 + rl < n)
              atomicAdd(&out[(size_t)sl[rl] * O_N + wave * 64 + cg * 16 + m_in],
                        acc[rg][cg][r]);
          }
    }
    __syncthreads();   // xs/sl safe to overwrite next chunk
  }
}

extern "C" void kernel_launch(void* const* d_in, const int* in_sizes, int n_in,
                              void* d_out, int out_size, void* d_ws, size_t ws_size,
                              hipStream_t stream) {
  const float* x      = (const float*)d_in[0];
  const int*   option = (const int*)d_in[1];
  const float* weight = (const float*)d_in[2];
  const float* bias   = (const float*)d_in[3];
  float* out = (float*)d_out;

  int* cnt  = (int*)d_ws;                    // 64 ints
  int* list = (int*)((char*)d_ws + 256);     // 64 * 2048 ints

  hipMemsetAsync(cnt, 0, E_N * sizeof(int), stream);
  bucket_kernel<<<B_N / 256, 256, 0, stream>>>(option, cnt, list);
  bias_init_kernel<<<(B_N * O_N / 4) / 256, 256, 0, stream>>>(option, bias, out);
  gemm_kernel<<<dim3(E_N, NSL), 512, 0, stream>>>(x, weight, cnt, list, out);
}

// Round 8
// 41.722 us; speedup vs baseline: 1.2938x; 1.2938x over previous
//
#include <hip/hip_runtime.h>

#define B_N 2048
#define E_N 64
#define D_N 512
#define O_N 512
#define MC  64   // sample rows per chunk
#define NT  16   // 32-k tiles

typedef __bf16 bf16x8 __attribute__((ext_vector_type(8)));
typedef float  f32x4  __attribute__((ext_vector_type(4)));

__device__ __forceinline__ unsigned short f2bf(float f) {
  unsigned int u = __float_as_uint(f);
  u = (u + 0x7FFFu + ((u >> 16) & 1u)) >> 16;  // RNE
  return (unsigned short)u;
}

// 8 blocks x 256: global-atomic bucketing (output is order-invariant).
__global__ __launch_bounds__(256)
void bucket_kernel(const int* __restrict__ opt, int* __restrict__ cnt,
                   int* __restrict__ list) {
  int b = blockIdx.x * 256 + threadIdx.x;
  int e = opt[b];
  int slot = atomicAdd(&cnt[e], 1);
  list[e * B_N + slot] = b;
}

// Grouped GEMM: block = (expert, 64-col slab), 8 waves = 2 m-groups(32 rows)
// x 4 col-groups(16 cols). Each wave streams its private W slice through a
// wave-private 4-slot ring of 2 KB LDS tiles fed by global_load_lds issued
// 3 tiles ahead; per-wave counted vmcnt(6) waits, NO barriers in the k-loop.
__global__ __launch_bounds__(512, 2)
void gemm_kernel(const float* __restrict__ x, const float* __restrict__ w,
                 const float* __restrict__ bias, const int* __restrict__ cnt,
                 const int* __restrict__ list, float* __restrict__ out) {
  __shared__ unsigned short xs[MC * 512];   // 64 KB bf16, XOR-swizzled rows
  __shared__ float ring[8][4][512];         // 64 KB: per-wave 4 x 2 KB W tiles

  const int e    = blockIdx.x;
  const int o0   = blockIdx.y * 64;
  const int t    = threadIdx.x;
  const int lane = t & 63;
  const int wave = t >> 6;
  const int wc   = wave & 3;    // col-group (16 cols)
  const int wg   = wave >> 2;   // m-group (32 rows)
  const int n    = cnt[e];
  if (n == 0) return;

  const float* wexp = w + (size_t)e * D_N * O_N;
  const int m_in = lane & 15;
  const int g    = lane >> 4;
  const int ocol = o0 + wc * 16 + m_in;
  const float bval = bias[e * O_N + ocol];
  const int* mylist = list + e * B_N;
  const int r0   = wg * 32 + m_in;       // A-row for acc0 (acc1 = +16)
  const int akey = (r0 & 7) << 3;

  // DMA source: instr h covers tile k-rows h*16+(lane>>2), cols (lane&3)*4..+3
  // -> dest lane-linear 16 B gives fp32 tile layout [krow&15][16c] + (krow>>4)*256.
  const float* wbase = wexp + o0 + wc * 16 +
                       (size_t)(lane >> 2) * O_N + (lane & 3) * 4;

#define DMA_T(TT) do {                                                         \
    const float* _s0 = wbase + (size_t)((TT) * 32) * O_N;                      \
    __builtin_amdgcn_global_load_lds(                                          \
        (const __attribute__((address_space(1))) void*)_s0,                    \
        (__attribute__((address_space(3))) void*)&ring[wave][(TT) & 3][0],     \
        16, 0, 0);                                                             \
    __builtin_amdgcn_global_load_lds(                                          \
        (const __attribute__((address_space(1))) void*)(_s0 + 16 * O_N),       \
        (__attribute__((address_space(3))) void*)&ring[wave][(TT) & 3][256],   \
        16, 0, 0);                                                             \
  } while (0)

#define COMPUTE(KT) do {                                                       \
    const float* wsp = &ring[wave][(KT) & 3][0];                               \
    const int kk = ((KT) * 32 + g * 8) ^ akey;                                 \
    union { uint4 u; bf16x8 v; } a0, a1;                                       \
    a0.u = *reinterpret_cast<const uint4*>(&xs[r0 * 512 + kk]);                \
    a1.u = *reinterpret_cast<const uint4*>(&xs[(r0 + 16) * 512 + kk]);         \
    union { unsigned short us[8]; bf16x8 v; } bw;                              \
    _Pragma("unroll")                                                          \
    for (int j = 0; j < 8; ++j) {                                              \
      const int k = g * 8 + j;                                                 \
      bw.us[j] = f2bf(wsp[((k & 15) << 4) + m_in + ((k >> 4) << 8)]);          \
    }                                                                          \
    acc0 = __builtin_amdgcn_mfma_f32_16x16x32_bf16(a0.v, bw.v, acc0, 0, 0, 0); \
    acc1 = __builtin_amdgcn_mfma_f32_16x16x32_bf16(a1.v, bw.v, acc1, 0, 0, 0); \
  } while (0)

#define WAITV(NSTR) asm volatile("s_waitcnt vmcnt(" NSTR ")" ::: "memory")

  for (int m0 = 0; m0 < n; m0 += MC) {
    __syncthreads();   // xs/ring safe to overwrite (drains everything)

    // ---- stage MC x 512 x rows, two phases: 16 loads -> regs, then cvt+write
    float4 xv[16];
#pragma unroll
    for (int i = 0; i < 16; ++i) {
      int idx = t + i * 512;
      int row = idx >> 7;          // 128 float4 per row
      int c4  = idx & 127;
      int s   = m0 + row;
      xv[i] = (s < n)
          ? *reinterpret_cast<const float4*>(x + (size_t)mylist[s] * D_N + c4 * 4)
          : make_float4(0.f, 0.f, 0.f, 0.f);
    }
#pragma unroll
    for (int i = 0; i < 16; ++i) {
      int idx = t + i * 512;
      int row = idx >> 7;
      int c4  = idx & 127;
      *reinterpret_cast<ushort4*>(&xs[row * 512 + ((c4 * 4) ^ ((row & 7) << 3))]) =
          make_ushort4(f2bf(xv[i].x), f2bf(xv[i].y), f2bf(xv[i].z), f2bf(xv[i].w));
    }
    __syncthreads();   // all vmem consumed; vmcnt == 0 entering the k-loop

    f32x4 acc0 = {0.f, 0.f, 0.f, 0.f};
    f32x4 acc1 = {0.f, 0.f, 0.f, 0.f};

    DMA_T(0); DMA_T(1); DMA_T(2);          // wave-private ring prologue (6 instrs)
#pragma unroll 1
    for (int kt = 0; kt < NT - 3; ++kt) {
      DMA_T(kt + 3);                       // 8 in flight
      WAITV("6");                          // tile kt landed (per-wave counter)
      COMPUTE(kt);
    }
    WAITV("4"); COMPUTE(NT - 3);           // unrolled tail: 13, 14, 15
    WAITV("2"); COMPUTE(NT - 2);
    WAITV("0"); COMPUTE(NT - 1);

    // D layout (m89-verified): col = lane&15, row = (lane>>4)*4 + reg
#pragma unroll
    for (int r = 0; r < 4; ++r) {
      int rl = wg * 32 + g * 4 + r;
      int s  = m0 + rl;
      if (s < n)  out[(size_t)mylist[s]  * O_N + ocol] = acc0[r] + bval;
      int s2 = s + 16;
      if (s2 < n) out[(size_t)mylist[s2] * O_N + ocol] = acc1[r] + bval;
    }
  }
#undef DMA_T
#undef COMPUTE
#undef WAITV
}

extern "C" void kernel_launch(void* const* d_in, const int* in_sizes, int n_in,
                              void* d_out, int out_size, void* d_ws, size_t ws_size,
                              hipStream_t stream) {
  const float* x      = (const float*)d_in[0];
  const int*   option = (const int*)d_in[1];
  const float* weight = (const float*)d_in[2];
  const float* bias   = (const float*)d_in[3];
  float* out = (float*)d_out;

  int* cnt  = (int*)d_ws;                    // 64 ints
  int* list = (int*)((char*)d_ws + 256);     // 64 * 2048 ints

  hipMemsetAsync(cnt, 0, E_N * sizeof(int), stream);
  bucket_kernel<<<B_N / 256, 256, 0, stream>>>(option, cnt, list);
  gemm_kernel<<<dim3(E_N, O_N / 64), 512, 0, stream>>>(x, weight, bias, cnt, list, out);
}